// Round 5
// baseline (364.572 us; speedup 1.0000x reference)
//
#include <hip/hip_runtime.h>
#include <math.h>

// ============================================================================
// GetImportantStruct — round 6: MLP (memory-level-parallelism) attack.
// r4 confirmed dur_us tracks kernel time 1:1; model gap points at the big
// movers being latency-bound (1-2 loads in flight per thread, one-shot waves)
// instead of BW-bound. Changes:
//  - k_score: 2 nodes per wave interleaved + persistent grid-stride loop.
//  - dest-driven streaming copies: pass3 records inverse maps esrc/nsrc;
//    k_copyE / k_copyN are fill-like grid-stride loops over dense output
//    (coalesced writes, ~contiguous gathers, many iterations per thread).
//  - k_bredge standalone (logic unchanged).
// Pipeline: memset + k_count + k_scan + k_score + k_pass1 + k_pass2 +
//           k_scanABC + k_pass3 + k_bredge + k_copyE + k_copyN (11 dispatches;
//           dispatch count measured ~free r1->r2).
// ============================================================================

// ---------------- parallel counting + scatter-target zeroing ----------------
__global__ void __launch_bounds__(512) k_count(
    const int* __restrict__ batch, int N,
    const int* __restrict__ br_batch, int N2,
    int* __restrict__ counts, int* __restrict__ counts2,
    int* __restrict__ dropcnt, int* __restrict__ brmask, int G){
  __shared__ int h1[512], h2[512];
  int t = threadIdx.x;
  h1[t] = 0; h2[t] = 0;
  __syncthreads();
  int gid    = blockIdx.x*blockDim.x + t;
  int stride = gridDim.x*blockDim.x;
  for (int i = gid; i < N;  i += stride) atomicAdd(&h1[batch[i]], 1);
  for (int i = gid; i < N2; i += stride) atomicAdd(&h2[br_batch[i]], 1);
  for (int i = gid; i < N2; i += stride) brmask[i] = 0;
  if (gid < G) dropcnt[gid] = 0;
  __syncthreads();
  if (t < G){
    if (h1[t]) atomicAdd(&counts[t],  h1[t]);
    if (h2[t]) atomicAdd(&counts2[t], h2[t]);
  }
}

// ---------------- G-length exclusive scans (single block, 512 threads) ------
__device__ __forceinline__ int scan512_excl_val(int v, int* s){
  int t = threadIdx.x;
  s[t] = v; __syncthreads();
  for (int off = 1; off < 512; off <<= 1){
    int add = (t >= off) ? s[t - off] : 0;
    __syncthreads();
    s[t] += add;
    __syncthreads();
  }
  int r = s[t] - v;
  __syncthreads();
  return r;
}

__global__ void __launch_bounds__(512) k_scan(
    const int* __restrict__ counts, const int* __restrict__ counts2,
    const int* __restrict__ edge_num, int G,
    int* __restrict__ node_off, int* __restrict__ node_off2,
    int* __restrict__ e_off){
  __shared__ int s[512];
  int t = threadIdx.x;
  int v1 = (t < G) ? counts[t]   : 0;
  int v2 = (t < G) ? counts2[t]  : 0;
  int v3 = (t < G) ? edge_num[t] : 0;
  int o1 = scan512_excl_val(v1, s);
  int o2 = scan512_excl_val(v2, s);
  int o3 = scan512_excl_val(v3, s);
  if (t < G){ node_off[t] = o1; node_off2[t] = o2; e_off[t] = o3; }
}

// ---------------- score / x_out / low / rem-init ----------------------------
// One wave per TWO nodes, persistent grid-stride: 4 independent 1KB loads in
// flight per wave + interleaved shfl chains (hides reduce latency).
__device__ __forceinline__ float dot4(float4 a, float4 w){
  return a.x*w.x + a.y*w.y + a.z*w.z + a.w*w.w;
}

__global__ void __launch_bounds__(256) k_score(
    const float* __restrict__ x, const float* __restrict__ W,
    const int* __restrict__ batch, const int* __restrict__ counts,
    const int* __restrict__ node_off,
    float* __restrict__ out_x, int* __restrict__ low, int* __restrict__ rem,
    int C, int N){
  int wid    = (blockIdx.x * blockDim.x + threadIdx.x) >> 6;
  int lane   = threadIdx.x & 63;
  int nwaves = (gridDim.x * blockDim.x) >> 6;
  const int nv = C >> 2;
  const bool fast = (nv == 128);             // wave-uniform
  const float4* W4 = (const float4*)W;
  float4 w0, w1;
  if (fast){ w0 = W4[lane]; w1 = W4[lane + 64]; }

  for (int nA = 2*wid; nA < N; nA += 2*nwaves){
    int nB = nA + 1;
    bool hasB = (nB < N);
    const float4* xA = (const float4*)(x + (size_t)nA * C);
    const float4* xB = (const float4*)(x + (size_t)nB * C);
    float accA = 0.f, accB = 0.f;
    float4 a0, a1, b0, b1;
    if (fast){
      a0 = xA[lane]; a1 = xA[lane + 64];
      if (hasB){ b0 = xB[lane]; b1 = xB[lane + 64]; }
      accA = dot4(a0, w0) + dot4(a1, w1);
      if (hasB) accB = dot4(b0, w0) + dot4(b1, w1);
    } else {
      for (int k = lane; k < nv; k += 64){
        float4 w = W4[k];
        accA += dot4(xA[k], w);
        if (hasB) accB += dot4(xB[k], w);
      }
    }
    #pragma unroll
    for (int d = 1; d < 64; d <<= 1){
      accA += __shfl_xor(accA, d, 64);
      accB += __shfl_xor(accB, d, 64);
    }
    float sA = 2.0f / (1.0f + expf(-accA / (float)C));
    float sB = 2.0f / (1.0f + expf(-accB / (float)C));
    if (lane == 0){
      int g    = batch[nA];
      int last = node_off[g] + counts[g] - 1;
      low[nA] = (accA < 0.0f) && (nA != last) ? 1 : 0;
      rem[nA] = -1;
      if (hasB){
        g    = batch[nB];
        last = node_off[g] + counts[g] - 1;
        low[nB] = (accB < 0.0f) && (nB != last) ? 1 : 0;
        rem[nB] = -1;
      }
    }
    float4* oA = (float4*)(out_x + (size_t)nA * C);
    float4* oB = (float4*)(out_x + (size_t)nB * C);
    if (fast){
      a0.x*=sA; a0.y*=sA; a0.z*=sA; a0.w*=sA;
      a1.x*=sA; a1.y*=sA; a1.z*=sA; a1.w*=sA;
      oA[lane] = a0; oA[lane + 64] = a1;
      if (hasB){
        b0.x*=sB; b0.y*=sB; b0.z*=sB; b0.w*=sB;
        b1.x*=sB; b1.y*=sB; b1.z*=sB; b1.w*=sB;
        oB[lane] = b0; oB[lane + 64] = b1;
      }
    } else {
      for (int k = lane; k < nv; k += 64){
        float4 a = xA[k];
        a.x*=sA; a.y*=sA; a.z*=sA; a.w*=sA;
        oA[k] = a;
        if (hasB){
          float4 bv = xB[k];
          bv.x*=sB; bv.y*=sB; bv.z*=sB; bv.w*=sB;
          oB[k] = bv;
        }
      }
    }
  }
}

// ---------------- edge -> graph lookup --------------------------------------
__device__ __forceinline__ int find_graph(const int* __restrict__ e_off, int G, int e){
  int lo = 0, hi = G - 1;            // largest g with e_off[g] <= e
  while (lo < hi){
    int mid = (lo + hi + 1) >> 1;
    if (e_off[mid] <= e) lo = mid; else hi = mid - 1;
  }
  return lo;
}

// ---------------- pass1: candidate edges (E) + br drop scatter (N) ----------
__global__ void k_pass1(const int* __restrict__ ei, const int* __restrict__ e_off,
                        const int* __restrict__ node_off, const int* __restrict__ node_off2,
                        const int* __restrict__ counts, const int* __restrict__ batch,
                        const int* __restrict__ low, const int* __restrict__ br_com_num,
                        int* __restrict__ rem, int* __restrict__ brmask,
                        int E, int N, int G){
  int e = blockIdx.x*blockDim.x + threadIdx.x;
  if (e < N && low[e]){                       // br-drop scatter for node e
    int g = batch[e];
    int d = e - node_off[g] + br_com_num[g] + node_off2[g];
    brmask[d] = 1;                            // 1 = dropped (mask pre-zeroed)
  }
  if (e >= E) return;
  int g  = find_graph(e_off, G, e);
  if (e - e_off[g] < 1) return;               // local_pos >= 1
  int dst  = ei[E + e];
  int last = node_off[g] + counts[g] - 1;
  if (dst != last) return;
  int src = ei[e];
  if (!low[src]) return;
  if (batch[src] != g) return;
  atomicMax(&rem[src], e);
}

// ---------------- pass2: blocksums for E (edges), N2 (br nodes), EB (br edges)
__global__ void k_pass2(const int* __restrict__ ei, const int* __restrict__ rem,
                        const int* __restrict__ e_off, const int* __restrict__ brmask,
                        const int* __restrict__ bi,
                        int* __restrict__ dropcnt,
                        int* __restrict__ bsumsA, int* __restrict__ bsumsB,
                        int* __restrict__ bsumsC,
                        int E, int N2, int EB, int G, int nbE, int nbN2){
  __shared__ int s[256];
  int b = blockIdx.x, t = threadIdx.x;
  int v = 0;
  if (b < nbE){
    int e = b*256 + t;
    if (e < E){
      v = (rem[ei[e]] != e) ? 1 : 0;
      if (!v){ int g = find_graph(e_off, G, e); atomicAdd(&dropcnt[g], 1); }
    }
  } else if (b < nbE + nbN2){
    int j = (b - nbE)*256 + t;
    v = (j < N2) ? (brmask[j] == 0) : 0;
  } else {
    int e = (b - nbE - nbN2)*256 + t;
    if (e < EB)
      v = (brmask[bi[e]] == 0 && brmask[bi[EB + e]] == 0) ? 1 : 0;
  }
  s[t] = v; __syncthreads();
  for (int off = 128; off > 0; off >>= 1){
    if (t < off) s[t] += s[t + off];
    __syncthreads();
  }
  if (t == 0){
    if (b < nbE)             bsumsA[b] = s[0];
    else if (b < nbE + nbN2) bsumsB[b - nbE] = s[0];
    else                     bsumsC[b - nbE - nbN2] = s[0];
  }
}

// ---------------- scan of all three block-sum arrays (3 blocks) -------------
__device__ void scan_bsums_dev(int* __restrict__ bsums, int nb, int* __restrict__ total){
  __shared__ int s[1024];
  int t = threadIdx.x;
  int v = (t < nb) ? bsums[t] : 0;
  s[t] = v; __syncthreads();
  for (int off = 1; off < 1024; off <<= 1){
    int add = (t >= off) ? s[t - off] : 0;
    __syncthreads();
    s[t] += add;
    __syncthreads();
  }
  if (t < nb)      bsums[t] = s[t] - v;
  if (t == nb - 1) *total   = s[t];
}

__global__ void k_scanABC(int* __restrict__ bsumsA, int nbA,
                          int* __restrict__ bsumsB, int nbB,
                          int* __restrict__ bsumsC, int nbC,
                          int* __restrict__ totals){
  if      (blockIdx.x == 0) scan_bsums_dev(bsumsA, nbA, &totals[0]);
  else if (blockIdx.x == 1) scan_bsums_dev(bsumsB, nbB, &totals[1]);
  else                      scan_bsums_dev(bsumsC, nbC, &totals[2]);
}

__device__ __forceinline__ int excl_scan256(int v, int* s){
  int t = threadIdx.x;
  s[t] = v; __syncthreads();
  for (int off = 1; off < 256; off <<= 1){
    int add = (t >= off) ? s[t - off] : 0;
    __syncthreads();
    s[t] += add;
    __syncthreads();
  }
  return s[t] - v;
}

// ---------------- pass3: edge scan-write + esrc + edgenum (E) |
//                  remap + nsrc scan-write (N2)
__global__ void k_pass3(const int* __restrict__ ei, const int* __restrict__ rem,
                        const int* __restrict__ bsumsA, const int* __restrict__ bsumsB,
                        const int* __restrict__ totals,
                        const int* __restrict__ edge_num, const int* __restrict__ dropcnt,
                        const int* __restrict__ brmask,
                        int* __restrict__ esrc, int* __restrict__ nsrc,
                        int* __restrict__ remap,
                        float* __restrict__ out, long long base0,
                        int E, int N2, int G, int DE, int nbE){
  __shared__ int s[256];
  int b = blockIdx.x, t = threadIdx.x;
  if (b < nbE){
    int e = b*256 + t;
    int keep = 0, src = 0, dst = 0;
    if (e < E){ src = ei[e]; dst = ei[E + e]; keep = (rem[src] != e) ? 1 : 0; }
    int excl = excl_scan256(keep, s);
    long long ek = totals[0];
    if (e < E && keep){
      int p = bsumsA[b] + excl;
      esrc[p] = e;
      out[base0 + p]      = (float)src;
      out[base0 + ek + p] = (float)dst;
    }
    if (b == 0){
      long long off3 = base0 + 2*ek + ek*(long long)DE;
      for (int g = t; g < G; g += 256)
        out[off3 + g] = (float)(edge_num[g] - dropcnt[g]);
    }
  } else {
    int j = (b - nbE)*256 + t;
    int keep = (j < N2) ? (brmask[j] == 0) : 0;
    int excl = excl_scan256(keep, s);
    if (j < N2){
      int p = bsumsB[b - nbE] + excl;
      remap[j] = keep ? p : -1;
      if (keep) nsrc[p] = j;
    }
  }
}

// ---------------- bredge: compacted br_index write (EB chunks) --------------
__global__ void k_bredge(const int* __restrict__ bi, const int* __restrict__ remap,
                         const int* __restrict__ bsumsC, const int* __restrict__ totals,
                         float* __restrict__ out, long long base0,
                         int G, int DE, int C, int EB){
  __shared__ int s[256];
  int b = blockIdx.x, t = threadIdx.x;
  long long ek = totals[0], nk = totals[1], kc = totals[2];
  long long off4 = base0 + 2*ek + ek*(long long)DE + G;        // br_feature_p
  long long off5 = off4 + nk*(long long)C;                     // br_index_p
  int e = b*256 + t;
  int r = -1, c = -1, keep = 0;
  if (e < EB){
    r = remap[bi[e]];
    c = remap[bi[EB + e]];
    keep = (r >= 0 && c >= 0) ? 1 : 0;
  }
  int excl = excl_scan256(keep, s);
  if (keep){
    int p = bsumsC[b] + excl;
    out[off5 + p]      = (float)r;
    out[off5 + kc + p] = (float)c;
  }
}

// ---------------- copyE: dest-driven inform row gather (fill-like) ----------
__global__ void __launch_bounds__(256) k_copyE(
    const int* __restrict__ esrc, const int* __restrict__ totals,
    const float* __restrict__ inform, float* __restrict__ out,
    long long base0, int DE){
  long long ek  = totals[0];
  int de4       = DE >> 2;
  long long tot = ek * (long long)de4;
  long long off2 = base0 + 2*ek;
  const float4* in4 = (const float4*)inform;
  bool pw2 = (de4 & (de4 - 1)) == 0;
  int  sh  = 31 - __clz(de4);
  long long idx    = (long long)blockIdx.x*blockDim.x + threadIdx.x;
  long long stride = (long long)gridDim.x*blockDim.x;
  for (; idx < tot; idx += stride){
    long long p = pw2 ? (idx >> sh) : (idx / de4);
    int j = (int)(idx - p * de4);
    int e = esrc[p];
    float4 v = in4[(size_t)e * de4 + j];
    ((float4*)(out + off2 + p * (long long)DE))[j] = v;
  }
}

// ---------------- copyN: dest-driven br_feature gather + br_batch -----------
__global__ void __launch_bounds__(256) k_copyN(
    const int* __restrict__ nsrc, const int* __restrict__ totals,
    const float* __restrict__ brf, const int* __restrict__ brb,
    float* __restrict__ out, long long base0, int G, int DE, int C){
  long long ek = totals[0], nk = totals[1], kc = totals[2];
  long long off4 = base0 + 2*ek + ek*(long long)DE + G;        // br_feature_p
  long long off6 = off4 + nk*(long long)C + 2*kc;              // br_batch_p
  int c4 = C >> 2;
  bool pw2 = (c4 & (c4 - 1)) == 0;
  int  sh  = 31 - __clz(c4);
  long long tot = nk * (long long)c4;
  const float4* in4 = (const float4*)brf;
  long long idx    = (long long)blockIdx.x*blockDim.x + threadIdx.x;
  long long stride = (long long)gridDim.x*blockDim.x;
  for (long long i = idx; i < tot; i += stride){
    long long p = pw2 ? (i >> sh) : (i / c4);
    int j = (int)(i - p * c4);
    int n = nsrc[p];
    float4 v = in4[(size_t)n * c4 + j];
    ((float4*)(out + off4 + p * (long long)C))[j] = v;
  }
  for (long long p = idx; p < nk; p += stride)
    out[off6 + p] = (float)brb[nsrc[p]];
}

// ============================================================================
extern "C" void kernel_launch(void* const* d_in, const int* in_sizes, int n_in,
                              void* d_out, int out_size, void* d_ws, size_t ws_size,
                              hipStream_t stream){
  const float* x           = (const float*)d_in[0];
  const int*   edge_index  = (const int*)  d_in[1];
  const int*   edge_num    = (const int*)  d_in[2];
  const float* edge_inform = (const float*)d_in[3];
  const int*   batch       = (const int*)  d_in[4];
  const float* br_feature  = (const float*)d_in[5];
  const int*   br_index    = (const int*)  d_in[6];
  const int*   br_batch    = (const int*)  d_in[7];
  const int*   br_com_num  = (const int*)  d_in[8];
  const float* W           = (const float*)d_in[9];
  float* out = (float*)d_out;

  const int C  = in_sizes[9];          // W is (1, C)
  const int N  = in_sizes[4];          // batch
  const int G  = in_sizes[2];          // edge_num
  const int E  = in_sizes[1] / 2;      // edge_index (2, E)
  const int DE = in_sizes[3] / E;      // edge_inform (E, DE)
  const int N2 = in_sizes[7];          // br_batch
  const int EB = in_sizes[6] / 2;      // br_index (2, EB)

  // ---- workspace layout (ints) ----
  int* ws        = (int*)d_ws;
  int* counts    = ws;                 // G   (zeroed by memset)
  int* counts2   = counts    + G;      // G   (zeroed by memset)
  int* dropcnt   = counts2   + G;      // G   (zeroed by k_count)
  int* brmask    = dropcnt   + G;      // N2  (zeroed by k_count)
  int* node_off  = brmask    + N2;     // G
  int* node_off2 = node_off  + G;      // G
  int* e_off     = node_off2 + G;      // G
  int* totals    = e_off     + G;      // 8: [0]=e_kept [1]=n_kept [2]=kc
  int* low       = totals    + 8;      // N
  int* rem       = low       + N;      // N
  int* remap     = rem       + N;      // N2
  int* esrc      = remap     + N2;     // E   (inverse map: kept pos -> edge)
  int* nsrc      = esrc      + E;      // N2  (inverse map: kept pos -> node)
  int* bsumsA    = nsrc      + N2;     // 1024
  int* bsumsB    = bsumsA    + 1024;   // 1024
  int* bsumsC    = bsumsB    + 1024;   // 1024

  const long long base0 = (long long)N * C;   // end of x_out chunk

  const int nbN2 = (N2 + 255) / 256;
  const int nbE  = (E  + 255) / 256;   // <= 1024
  const int nbB  = (EB + 255) / 256;   // <= 1024

  hipMemsetAsync(counts, 0, sizeof(int) * 2 * (size_t)G, stream);

  k_count<<<64, 512, 0, stream>>>(batch, N, br_batch, N2,
                                  counts, counts2, dropcnt, brmask, G);

  k_scan<<<1, 512, 0, stream>>>(counts, counts2, edge_num, G,
                                node_off, node_off2, e_off);

  k_score<<<2048, 256, 0, stream>>>(x, W, batch, counts, node_off,
                                    out, low, rem, C, N);

  k_pass1<<<(max(E, N) + 255) / 256, 256, 0, stream>>>(
      edge_index, e_off, node_off, node_off2, counts, batch, low, br_com_num,
      rem, brmask, E, N, G);

  k_pass2<<<nbE + nbN2 + nbB, 256, 0, stream>>>(edge_index, rem, e_off, brmask,
                                                br_index, dropcnt,
                                                bsumsA, bsumsB, bsumsC,
                                                E, N2, EB, G, nbE, nbN2);

  k_scanABC<<<3, 1024, 0, stream>>>(bsumsA, nbE, bsumsB, nbN2, bsumsC, nbB,
                                    totals);

  k_pass3<<<nbE + nbN2, 256, 0, stream>>>(edge_index, rem, bsumsA, bsumsB, totals,
                                          edge_num, dropcnt, brmask,
                                          esrc, nsrc, remap, out, base0,
                                          E, N2, G, DE, nbE);

  k_bredge<<<nbB, 256, 0, stream>>>(br_index, remap, bsumsC, totals,
                                    out, base0, G, DE, C, EB);

  k_copyE<<<2048, 256, 0, stream>>>(esrc, totals, edge_inform, out, base0, DE);

  k_copyN<<<2048, 256, 0, stream>>>(nsrc, totals, br_feature, br_batch,
                                    out, base0, G, DE, C);
}